// Round 1
// baseline (3192.135 us; speedup 1.0000x reference)
//
#include <hip/hip_runtime.h>

constexpr int NN = 100000;
constexpr int NE = 1600000;
constexpr int IN_DIM = 300;
constexpr int HID = 128;
constexpr int NC = 3;
constexpr int NA = 2048;

// ---------------- degree / norm ----------------
__global__ void k_deg(const int* __restrict__ dst, float* __restrict__ deg) {
    int i = blockIdx.x * blockDim.x + threadIdx.x;
    if (i < NE) atomicAdd(&deg[dst[i]], 1.0f);
}

__global__ void k_dis(float* __restrict__ dis) {
    int i = blockIdx.x * blockDim.x + threadIdx.x;
    if (i < NN) dis[i] = rsqrtf(dis[i] + 1.0f);   // +1 self loop; always > 0
}

__global__ void k_flags(const int* __restrict__ asp, unsigned char* __restrict__ flags) {
    int i = blockIdx.x * blockDim.x + threadIdx.x;
    if (i < NA) flags[asp[i]] = 1;
}

// ---------------- fp32 GEMM: C[M,128] = A[M,K] @ B[K,128] ----------------
// 64-row x 128-col tile per block, 256 threads, each thread 8 rows x 4 cols.
template <int K, int BK>
__global__ __launch_bounds__(256) void k_gemm(const float* __restrict__ A,
                                              const float* __restrict__ B,
                                              float* __restrict__ C, int M) {
    __shared__ float As[BK][64];    // transposed: As[k][r]
    __shared__ float Bs[BK][128];
    const int t = threadIdx.x;
    const int row0 = blockIdx.x * 64;
    const int cg = t & 31;          // column group: 4 cols
    const int rg = t >> 5;          // row group: 8 rows

    float acc[8][4];
#pragma unroll
    for (int i = 0; i < 8; ++i)
#pragma unroll
        for (int j = 0; j < 4; ++j) acc[i][j] = 0.f;

    for (int k0 = 0; k0 < K; k0 += BK) {
        for (int i = t; i < 64 * BK; i += 256) {
            int r = i / BK, k = i % BK;
            int gr = row0 + r;
            As[k][r] = (gr < M) ? A[(long)gr * K + k0 + k] : 0.f;
        }
        for (int i = t; i < BK * 128; i += 256) {
            int k = i >> 7, c = i & 127;
            Bs[k][c] = B[(long)(k0 + k) * 128 + c];
        }
        __syncthreads();
#pragma unroll
        for (int k = 0; k < BK; ++k) {
            const float4 b4 = *reinterpret_cast<const float4*>(&Bs[k][cg * 4]);
            float a[8];
#pragma unroll
            for (int i = 0; i < 8; ++i) a[i] = As[k][rg * 8 + i];
#pragma unroll
            for (int i = 0; i < 8; ++i) {
                acc[i][0] += a[i] * b4.x;
                acc[i][1] += a[i] * b4.y;
                acc[i][2] += a[i] * b4.z;
                acc[i][3] += a[i] * b4.w;
            }
        }
        __syncthreads();
    }
#pragma unroll
    for (int i = 0; i < 8; ++i) {
        int gr = row0 + rg * 8 + i;
        if (gr < M) {
            *reinterpret_cast<float4*>(&C[(long)gr * 128 + cg * 4]) =
                make_float4(acc[i][0], acc[i][1], acc[i][2], acc[i][3]);
        }
    }
}

// ---------------- edge scatter: out[dst] += dis[s]*dis[d] * h[src] ----------------
// 32 threads per edge, float4 per thread (128 dims).
template <bool USE_FLAGS>
__global__ void k_scatter(const int* __restrict__ src, const int* __restrict__ dst,
                          const float* __restrict__ dis, const float* __restrict__ h,
                          float* __restrict__ out, const unsigned char* __restrict__ flags) {
    long idx = (long)blockIdx.x * blockDim.x + threadIdx.x;
    int e = (int)(idx >> 5);
    int part = (int)(idx & 31);
    if (e >= NE) return;
    int d = dst[e];
    if constexpr (USE_FLAGS) {
        if (!flags[d]) return;
    }
    int s = src[e];
    float n = dis[s] * dis[d];
    const float4 v = *reinterpret_cast<const float4*>(&h[(long)s * HID + part * 4]);
    float* o = &out[(long)d * HID + part * 4];
    atomicAdd(o + 0, n * v.x);
    atomicAdd(o + 1, n * v.y);
    atomicAdd(o + 2, n * v.z);
    atomicAdd(o + 3, n * v.w);
}

// ---------------- epilogue 1: h2in = relu(agg1 + dis^2*h1 + b1), in place over agg ----------------
__global__ void k_epi1(float* __restrict__ agg, const float* __restrict__ h1,
                       const float* __restrict__ dis, const float* __restrict__ b1) {
    long i = (long)blockIdx.x * blockDim.x + threadIdx.x;   // over NN*32 float4 groups
    if (i >= (long)NN * 32) return;
    int node = (int)(i >> 5);
    int part = (int)(i & 31);
    float d2 = dis[node];
    d2 *= d2;
    float4 a = *reinterpret_cast<const float4*>(&agg[i * 4]);
    float4 h = *reinterpret_cast<const float4*>(&h1[i * 4]);
    float4 b = *reinterpret_cast<const float4*>(&b1[part * 4]);
    float4 r;
    r.x = fmaxf(a.x + d2 * h.x + b.x, 0.f);
    r.y = fmaxf(a.y + d2 * h.y + b.y, 0.f);
    r.z = fmaxf(a.z + d2 * h.z + b.z, 0.f);
    r.w = fmaxf(a.w + d2 * h.w + b.w, 0.f);
    *reinterpret_cast<float4*>(&agg[i * 4]) = r;
}

// ---------------- final: per-aspect self-loop + b2, then @Wc + bc ----------------
__global__ void k_final(const int* __restrict__ asp, const float* __restrict__ agg2,
                        const float* __restrict__ t2, const float* __restrict__ dis,
                        const float* __restrict__ b2, const float* __restrict__ Wc,
                        const float* __restrict__ bc, float* __restrict__ out) {
    int a = blockIdx.x * blockDim.x + threadIdx.x;
    if (a >= NA) return;
    int node = asp[a];
    float d2 = dis[node];
    d2 *= d2;
    float acc0 = bc[0], acc1 = bc[1], acc2 = bc[2];
    for (int d = 0; d < HID; ++d) {
        float v = agg2[(long)node * HID + d] + d2 * t2[(long)node * HID + d] + b2[d];
        acc0 += v * Wc[d * 3 + 0];
        acc1 += v * Wc[d * 3 + 1];
        acc2 += v * Wc[d * 3 + 2];
    }
    out[a * 3 + 0] = acc0;
    out[a * 3 + 1] = acc1;
    out[a * 3 + 2] = acc2;
}

extern "C" void kernel_launch(void* const* d_in, const int* in_sizes, int n_in,
                              void* d_out, int out_size, void* d_ws, size_t ws_size,
                              hipStream_t stream) {
    const float* features = (const float*)d_in[0];
    const int* ei = (const int*)d_in[1];       // [2, NE]
    const int* src = ei;
    const int* dst = ei + NE;
    const int* asp = (const int*)d_in[2];
    const float* W1 = (const float*)d_in[3];
    const float* b1 = (const float*)d_in[4];
    const float* W2 = (const float*)d_in[5];
    const float* b2 = (const float*)d_in[6];
    const float* Wc = (const float*)d_in[7];
    const float* bc = (const float*)d_in[8];
    float* out = (float*)d_out;

    char* ws = (char*)d_ws;
    float* dis = (float*)ws;                                    // NN floats (400000 B)
    unsigned char* flags = (unsigned char*)(ws + 400384);       // NN bytes
    float* bufA = (float*)(ws + 500480);                        // NN*HID floats (h1, then t2)
    float* bufB = (float*)(ws + 500480 + (size_t)NN * HID * 4); // NN*HID floats (agg1/h2in, then agg2)

    // norm + flags
    hipMemsetAsync(dis, 0, NN * sizeof(float), stream);
    hipMemsetAsync(flags, 0, NN, stream);
    k_deg<<<(NE + 255) / 256, 256, 0, stream>>>(dst, dis);
    k_dis<<<(NN + 255) / 256, 256, 0, stream>>>(dis);
    k_flags<<<(NA + 255) / 256, 256, 0, stream>>>(asp, flags);

    // layer 1
    k_gemm<IN_DIM, 20><<<(NN + 63) / 64, 256, 0, stream>>>(features, W1, bufA, NN);
    hipMemsetAsync(bufB, 0, (size_t)NN * HID * 4, stream);
    {
        long threads = (long)NE * 32;
        k_scatter<false><<<(int)((threads + 255) / 256), 256, 0, stream>>>(
            src, dst, dis, bufA, bufB, nullptr);
    }
    {
        long threads = (long)NN * 32;
        k_epi1<<<(int)((threads + 255) / 256), 256, 0, stream>>>(bufB, bufA, dis, b1);
    }

    // layer 2 (only aspect rows matter downstream -> flag-filtered scatter)
    k_gemm<HID, 32><<<(NN + 63) / 64, 256, 0, stream>>>(bufB, W2, bufA, NN);
    hipMemsetAsync(bufB, 0, (size_t)NN * HID * 4, stream);
    {
        long threads = (long)NE * 32;
        k_scatter<true><<<(int)((threads + 255) / 256), 256, 0, stream>>>(
            src, dst, dis, bufA, bufB, flags);
    }

    // classifier
    k_final<<<(NA + 255) / 256, 256, 0, stream>>>(asp, bufB, bufA, dis, b2, Wc, bc, out);
}

// Round 2
// 645.979 us; speedup vs baseline: 4.9415x; 4.9415x over previous
//
#include <hip/hip_runtime.h>

constexpr int NN = 100000;
constexpr int NE = 1600000;
constexpr int IN_DIM = 300;
constexpr int HID = 128;
constexpr int NA = 2048;

// ---------------- degree (int) ----------------
__global__ void k_deg(const int* __restrict__ dst, int* __restrict__ degi) {
    int i = blockIdx.x * blockDim.x + threadIdx.x;
    if (i < NE) atomicAdd(&degi[dst[i]], 1);
}

__global__ void k_dis(const int* __restrict__ degi, float* __restrict__ dis) {
    int i = blockIdx.x * blockDim.x + threadIdx.x;
    if (i < NN) dis[i] = rsqrtf((float)degi[i] + 1.0f);   // +1 self loop
}

// ---------------- hierarchical exclusive scan over degi -> off ----------------
__global__ __launch_bounds__(1024) void k_scan_local(const int* __restrict__ degi,
                                                     int* __restrict__ off,
                                                     int* __restrict__ blksum) {
    __shared__ int sh[1024];
    int t = threadIdx.x;
    int base = blockIdx.x * 1024;
    int v = (base + t < NN) ? degi[base + t] : 0;
    sh[t] = v;
    __syncthreads();
    for (int s = 1; s < 1024; s <<= 1) {
        int a = (t >= s) ? sh[t - s] : 0;
        __syncthreads();
        sh[t] += a;
        __syncthreads();
    }
    if (base + t < NN) off[base + t] = sh[t] - v;   // exclusive
    if (t == 1023) blksum[blockIdx.x] = sh[1023];
}

__global__ __launch_bounds__(128) void k_scan_blk(int* __restrict__ blksum, int nb) {
    __shared__ int sh[128];
    int t = threadIdx.x;
    int v = (t < nb) ? blksum[t] : 0;
    sh[t] = v;
    __syncthreads();
    for (int s = 1; s < 128; s <<= 1) {
        int a = (t >= s) ? sh[t - s] : 0;
        __syncthreads();
        sh[t] += a;
        __syncthreads();
    }
    if (t < nb) blksum[t] = sh[t] - v;   // exclusive
}

__global__ void k_scan_add(int* __restrict__ off, const int* __restrict__ blksum) {
    int i = blockIdx.x * blockDim.x + threadIdx.x;
    if (i < NN) off[i] += blksum[i >> 10];
}

// ---------------- bucket fill: csr[pos] = src, advancing off -> off_post ----------------
__global__ void k_fill(const int* __restrict__ src, const int* __restrict__ dst,
                       int* __restrict__ off, int* __restrict__ csr) {
    int e = blockIdx.x * blockDim.x + threadIdx.x;
    if (e < NE) {
        int d = dst[e];
        int pos = atomicAdd(&off[d], 1);
        csr[pos] = src[e];
    }
}

// ---------------- fp32 GEMM: C[M,128] = A[M,K] @ B[K,128] ----------------
template <int K, int BK>
__global__ __launch_bounds__(256) void k_gemm(const float* __restrict__ A,
                                              const float* __restrict__ B,
                                              float* __restrict__ C, int M) {
    __shared__ float As[BK][64];
    __shared__ float Bs[BK][128];
    const int t = threadIdx.x;
    const int row0 = blockIdx.x * 64;
    const int cg = t & 31;
    const int rg = t >> 5;

    float acc[8][4];
#pragma unroll
    for (int i = 0; i < 8; ++i)
#pragma unroll
        for (int j = 0; j < 4; ++j) acc[i][j] = 0.f;

    for (int k0 = 0; k0 < K; k0 += BK) {
        for (int i = t; i < 64 * BK; i += 256) {
            int r = i / BK, k = i % BK;
            int gr = row0 + r;
            As[k][r] = (gr < M) ? A[(long)gr * K + k0 + k] : 0.f;
        }
        for (int i = t; i < BK * 128; i += 256) {
            int k = i >> 7, c = i & 127;
            Bs[k][c] = B[(long)(k0 + k) * 128 + c];
        }
        __syncthreads();
#pragma unroll
        for (int k = 0; k < BK; ++k) {
            const float4 b4 = *reinterpret_cast<const float4*>(&Bs[k][cg * 4]);
            float a[8];
#pragma unroll
            for (int i = 0; i < 8; ++i) a[i] = As[k][rg * 8 + i];
#pragma unroll
            for (int i = 0; i < 8; ++i) {
                acc[i][0] += a[i] * b4.x;
                acc[i][1] += a[i] * b4.y;
                acc[i][2] += a[i] * b4.z;
                acc[i][3] += a[i] * b4.w;
            }
        }
        __syncthreads();
    }
#pragma unroll
    for (int i = 0; i < 8; ++i) {
        int gr = row0 + rg * 8 + i;
        if (gr < M) {
            *reinterpret_cast<float4*>(&C[(long)gr * 128 + cg * 4]) =
                make_float4(acc[i][0], acc[i][1], acc[i][2], acc[i][3]);
        }
    }
}

// ---------------- gather layer 1 (fused: agg + self-loop + b1 + relu) ----------------
// one wave per node; lane owns dims [2*lane, 2*lane+1]
__global__ __launch_bounds__(256) void k_gather1(const int* __restrict__ csr,
                                                 const int* __restrict__ offpost,
                                                 const float* __restrict__ dis,
                                                 const float* __restrict__ h1,
                                                 const float* __restrict__ b1,
                                                 float* __restrict__ out) {
    int wave = threadIdx.x >> 6;
    int lane = threadIdx.x & 63;
    int n = blockIdx.x * 4 + wave;
    if (n >= NN) return;
    int start = (n == 0) ? 0 : offpost[n - 1];
    int end = offpost[n];
    float dn = dis[n];
    float2 acc = make_float2(0.f, 0.f);
    for (int i = start; i < end; ++i) {
        int s = csr[i];
        float w = dis[s] * dn;
        float2 v = *reinterpret_cast<const float2*>(&h1[(long)s * HID + lane * 2]);
        acc.x += w * v.x;
        acc.y += w * v.y;
    }
    float d2 = dn * dn;
    float2 hv = *reinterpret_cast<const float2*>(&h1[(long)n * HID + lane * 2]);
    float2 bv = *reinterpret_cast<const float2*>(&b1[lane * 2]);
    float2 r;
    r.x = fmaxf(acc.x + d2 * hv.x + bv.x, 0.f);
    r.y = fmaxf(acc.y + d2 * hv.y + bv.y, 0.f);
    *reinterpret_cast<float2*>(&out[(long)n * HID + lane * 2]) = r;
}

// ---------------- gather layer 2 (aspects only) fused with classifier ----------------
__global__ __launch_bounds__(256) void k_gather2(const int* __restrict__ asp,
                                                 const int* __restrict__ csr,
                                                 const int* __restrict__ offpost,
                                                 const float* __restrict__ dis,
                                                 const float* __restrict__ t2,
                                                 const float* __restrict__ b2,
                                                 const float* __restrict__ Wc,
                                                 const float* __restrict__ bc,
                                                 float* __restrict__ out) {
    int wave = threadIdx.x >> 6;
    int lane = threadIdx.x & 63;
    int a = blockIdx.x * 4 + wave;
    if (a >= NA) return;
    int n = asp[a];
    int start = (n == 0) ? 0 : offpost[n - 1];
    int end = offpost[n];
    float dn = dis[n];
    float2 acc = make_float2(0.f, 0.f);
    for (int i = start; i < end; ++i) {
        int s = csr[i];
        float w = dis[s] * dn;
        float2 v = *reinterpret_cast<const float2*>(&t2[(long)s * HID + lane * 2]);
        acc.x += w * v.x;
        acc.y += w * v.y;
    }
    float d2 = dn * dn;
    float2 hv = *reinterpret_cast<const float2*>(&t2[(long)n * HID + lane * 2]);
    float vx = acc.x + d2 * hv.x + b2[2 * lane];
    float vy = acc.y + d2 * hv.y + b2[2 * lane + 1];
    float l0 = vx * Wc[(2 * lane) * 3 + 0] + vy * Wc[(2 * lane + 1) * 3 + 0];
    float l1 = vx * Wc[(2 * lane) * 3 + 1] + vy * Wc[(2 * lane + 1) * 3 + 1];
    float l2 = vx * Wc[(2 * lane) * 3 + 2] + vy * Wc[(2 * lane + 1) * 3 + 2];
#pragma unroll
    for (int s = 32; s > 0; s >>= 1) {
        l0 += __shfl_xor(l0, s);
        l1 += __shfl_xor(l1, s);
        l2 += __shfl_xor(l2, s);
    }
    if (lane == 0) {
        out[a * 3 + 0] = l0 + bc[0];
        out[a * 3 + 1] = l1 + bc[1];
        out[a * 3 + 2] = l2 + bc[2];
    }
}

extern "C" void kernel_launch(void* const* d_in, const int* in_sizes, int n_in,
                              void* d_out, int out_size, void* d_ws, size_t ws_size,
                              hipStream_t stream) {
    const float* features = (const float*)d_in[0];
    const int* ei = (const int*)d_in[1];
    const int* src = ei;
    const int* dst = ei + NE;
    const int* asp = (const int*)d_in[2];
    const float* W1 = (const float*)d_in[3];
    const float* b1 = (const float*)d_in[4];
    const float* W2 = (const float*)d_in[5];
    const float* b2 = (const float*)d_in[6];
    const float* Wc = (const float*)d_in[7];
    const float* bc = (const float*)d_in[8];
    float* out = (float*)d_out;

    char* ws = (char*)d_ws;
    float* dis   = (float*)(ws + 0);            // 400000 B
    int*   degi  = (int*)  (ws + 400384);       // 400000 B
    int*   off   = (int*)  (ws + 800768);       // 400000 B
    int*   blksum= (int*)  (ws + 1201152);      // 1024 B
    int*   csr   = (int*)  (ws + 1202176);      // 6400000 B
    float* bufA  = (float*)(ws + 7602432);      // 51200000 B (h1, then t2)
    float* bufB  = (float*)(ws + 58802432);     // 51200000 B (h2in)

    const int NB = (NN + 1023) / 1024;  // 98

    // degree + norm
    hipMemsetAsync(degi, 0, NN * sizeof(int), stream);
    k_deg<<<(NE + 255) / 256, 256, 0, stream>>>(dst, degi);
    k_dis<<<(NN + 255) / 256, 256, 0, stream>>>(degi, dis);

    // CSR build
    k_scan_local<<<NB, 1024, 0, stream>>>(degi, off, blksum);
    k_scan_blk<<<1, 128, 0, stream>>>(blksum, NB);
    k_scan_add<<<(NN + 255) / 256, 256, 0, stream>>>(off, blksum);
    k_fill<<<(NE + 255) / 256, 256, 0, stream>>>(src, dst, off, csr);

    // layer 1: h1 = X@W1 ; h2in = relu(agg(h1) + dis^2*h1 + b1)
    k_gemm<IN_DIM, 20><<<(NN + 63) / 64, 256, 0, stream>>>(features, W1, bufA, NN);
    k_gather1<<<(NN + 3) / 4, 256, 0, stream>>>(csr, off, dis, bufA, b1, bufB);

    // layer 2: t2 = h2in@W2 ; logits per aspect
    k_gemm<HID, 32><<<(NN + 63) / 64, 256, 0, stream>>>(bufB, W2, bufA, NN);
    k_gather2<<<(NA + 3) / 4, 256, 0, stream>>>(asp, csr, off, dis, bufA, b2, Wc, bc, out);
}

// Round 3
// 532.586 us; speedup vs baseline: 5.9936x; 1.2129x over previous
//
#include <hip/hip_runtime.h>

constexpr int NN = 100000;
constexpr int NE = 1600000;
constexpr int IN_DIM = 300;
constexpr int HID = 128;
constexpr int NA = 2048;
constexpr int KP1 = 320;   // padded K for GEMM1 Bt
constexpr int KP2 = 128;

using short8 = __attribute__((ext_vector_type(8))) short;
using f32x4  = __attribute__((ext_vector_type(4))) float;

__device__ inline unsigned short f2bf(float x) {
    unsigned u = __float_as_uint(x);
    unsigned r = u + 0x7FFFu + ((u >> 16) & 1u);
    return (unsigned short)(r >> 16);
}
__device__ inline float bf2f(unsigned short h) {
    return __uint_as_float(((unsigned)h) << 16);
}

// ---------------- degree (int) ----------------
__global__ void k_deg(const int* __restrict__ dst, int* __restrict__ degi) {
    int i = blockIdx.x * blockDim.x + threadIdx.x;
    if (i < NE) atomicAdd(&degi[dst[i]], 1);
}

__global__ void k_dis(const int* __restrict__ degi, float* __restrict__ dis) {
    int i = blockIdx.x * blockDim.x + threadIdx.x;
    if (i < NN) dis[i] = rsqrtf((float)degi[i] + 1.0f);   // +1 self loop
}

// ---------------- hierarchical exclusive scan over degi -> off ----------------
__global__ __launch_bounds__(1024) void k_scan_local(const int* __restrict__ degi,
                                                     int* __restrict__ off,
                                                     int* __restrict__ blksum) {
    __shared__ int sh[1024];
    int t = threadIdx.x;
    int base = blockIdx.x * 1024;
    int v = (base + t < NN) ? degi[base + t] : 0;
    sh[t] = v;
    __syncthreads();
    for (int s = 1; s < 1024; s <<= 1) {
        int a = (t >= s) ? sh[t - s] : 0;
        __syncthreads();
        sh[t] += a;
        __syncthreads();
    }
    if (base + t < NN) off[base + t] = sh[t] - v;   // exclusive
    if (t == 1023) blksum[blockIdx.x] = sh[1023];
}

__global__ __launch_bounds__(128) void k_scan_blk(int* __restrict__ blksum, int nb) {
    __shared__ int sh[128];
    int t = threadIdx.x;
    int v = (t < nb) ? blksum[t] : 0;
    sh[t] = v;
    __syncthreads();
    for (int s = 1; s < 128; s <<= 1) {
        int a = (t >= s) ? sh[t - s] : 0;
        __syncthreads();
        sh[t] += a;
        __syncthreads();
    }
    if (t < nb) blksum[t] = sh[t] - v;   // exclusive
}

__global__ void k_scan_add(int* __restrict__ off, const int* __restrict__ blksum) {
    int i = blockIdx.x * blockDim.x + threadIdx.x;
    if (i < NN) off[i] += blksum[i >> 10];
}

// ---------------- bucket fill ----------------
__global__ void k_fill(const int* __restrict__ src, const int* __restrict__ dst,
                       int* __restrict__ off, int* __restrict__ csr) {
    int e = blockIdx.x * blockDim.x + threadIdx.x;
    if (e < NE) {
        int d = dst[e];
        int pos = atomicAdd(&off[d], 1);
        csr[pos] = src[e];
    }
}

// ---------------- B pre-split: Bt_hi/Bt_lo[col][Kpad] (bf16) ----------------
__global__ void k_prepB(const float* __restrict__ B, unsigned short* __restrict__ bt_hi,
                        unsigned short* __restrict__ bt_lo, int K, int Kpad) {
    int i = blockIdx.x * blockDim.x + threadIdx.x;
    if (i >= Kpad * 128) return;
    int k = i >> 7, c = i & 127;
    float v = (k < K) ? B[k * 128 + c] : 0.f;
    unsigned short hi = f2bf(v);
    unsigned short lo = f2bf(v - bf2f(hi));
    bt_hi[c * Kpad + k] = hi;
    bt_lo[c * Kpad + k] = lo;
}

// ---------------- split-bf16 MFMA GEMM: C[M,128] = A[M,K] @ B[K,128] ----------------
// 128 rows/block, 4 waves x (32 rows x 128 cols). A staged fp32 in LDS (36-float
// row stride -> balanced banks), converted hi/lo in-register. B frags from global.
template <int K, int KPAD>
__global__ __launch_bounds__(256) void k_gemm_mfma(const float* __restrict__ A,
        const unsigned short* __restrict__ bt_hi, const unsigned short* __restrict__ bt_lo,
        float* __restrict__ C, int M) {
    __shared__ float As[128 * 36];
    const int t = threadIdx.x;
    const int w = t >> 6;
    const int l = t & 63;
    const int row0 = blockIdx.x * 128;
    const int lr = l & 15;       // fragment row/col
    const int lg = l >> 4;       // k-group (0..3)

    f32x4 acc[2][8];
#pragma unroll
    for (int rt = 0; rt < 2; ++rt)
#pragma unroll
        for (int ct = 0; ct < 8; ++ct) acc[rt][ct] = (f32x4){0.f, 0.f, 0.f, 0.f};

    const int NT = (K + 31) / 32;
    for (int kt = 0; kt < NT; ++kt) {
        const int k0 = kt * 32;
        // stage A tile [128][32] fp32
#pragma unroll
        for (int i = t; i < 512; i += 256) {
            int r = i >> 2, q = i & 3;
            int gr = row0 + r;
            float* dp = &As[r * 36 + q * 8];
            const float* sp = &A[(long)gr * K + k0 + q * 8];
            if (gr < M && (k0 + q * 8 + 8) <= K) {
                float4 v0 = *(const float4*)(sp);
                float4 v1 = *(const float4*)(sp + 4);
                *(float4*)(dp) = v0;
                *(float4*)(dp + 4) = v1;
            } else {
#pragma unroll
                for (int j = 0; j < 8; ++j)
                    dp[j] = (gr < M && (k0 + q * 8 + j) < K) ? sp[j] : 0.f;
            }
        }
        __syncthreads();
        // A fragments (hi/lo)
        short8 ahi[2], alo[2];
#pragma unroll
        for (int rt = 0; rt < 2; ++rt) {
            const float* p = &As[(w * 32 + rt * 16 + lr) * 36 + lg * 8];
            float4 v0 = *(const float4*)(p);
            float4 v1 = *(const float4*)(p + 4);
            float av[8] = {v0.x, v0.y, v0.z, v0.w, v1.x, v1.y, v1.z, v1.w};
#pragma unroll
            for (int j = 0; j < 8; ++j) {
                unsigned short hi = f2bf(av[j]);
                ahi[rt][j] = (short)hi;
                alo[rt][j] = (short)f2bf(av[j] - bf2f(hi));
            }
        }
        // B fragments + MFMA
#pragma unroll
        for (int ct = 0; ct < 8; ++ct) {
            const int c = ct * 16 + lr;
            const long boff = (long)c * KPAD + k0 + lg * 8;
            short8 bhi = *(const short8*)(&bt_hi[boff]);
            short8 blo = *(const short8*)(&bt_lo[boff]);
#pragma unroll
            for (int rt = 0; rt < 2; ++rt) {
                acc[rt][ct] = __builtin_amdgcn_mfma_f32_16x16x32_bf16(ahi[rt], bhi, acc[rt][ct], 0, 0, 0);
                acc[rt][ct] = __builtin_amdgcn_mfma_f32_16x16x32_bf16(alo[rt], bhi, acc[rt][ct], 0, 0, 0);
                acc[rt][ct] = __builtin_amdgcn_mfma_f32_16x16x32_bf16(ahi[rt], blo, acc[rt][ct], 0, 0, 0);
            }
        }
        __syncthreads();
    }
    // epilogue: C/D layout col=lane&15, row=(lane>>4)*4+reg
#pragma unroll
    for (int rt = 0; rt < 2; ++rt)
#pragma unroll
        for (int ct = 0; ct < 8; ++ct)
#pragma unroll
            for (int r = 0; r < 4; ++r) {
                int row = row0 + w * 32 + rt * 16 + lg * 4 + r;
                if (row < M) C[(long)row * 128 + ct * 16 + lr] = acc[rt][ct][r];
            }
}

// ---------------- gather layer 1 (fused: agg + self-loop + b1 + relu) ----------------
__global__ __launch_bounds__(256) void k_gather1(const int* __restrict__ csr,
                                                 const int* __restrict__ offpost,
                                                 const float* __restrict__ dis,
                                                 const float* __restrict__ h1,
                                                 const float* __restrict__ b1,
                                                 float* __restrict__ out) {
    int wave = threadIdx.x >> 6;
    int lane = threadIdx.x & 63;
    int n = blockIdx.x * 4 + wave;
    if (n >= NN) return;
    int start = (n == 0) ? 0 : offpost[n - 1];
    int end = offpost[n];
    float dn = dis[n];
    float2 acc = make_float2(0.f, 0.f);
    for (int i = start; i < end; ++i) {
        int s = csr[i];
        float w = dis[s] * dn;
        float2 v = *reinterpret_cast<const float2*>(&h1[(long)s * HID + lane * 2]);
        acc.x += w * v.x;
        acc.y += w * v.y;
    }
    float d2 = dn * dn;
    float2 hv = *reinterpret_cast<const float2*>(&h1[(long)n * HID + lane * 2]);
    float2 bv = *reinterpret_cast<const float2*>(&b1[lane * 2]);
    float2 r;
    r.x = fmaxf(acc.x + d2 * hv.x + bv.x, 0.f);
    r.y = fmaxf(acc.y + d2 * hv.y + bv.y, 0.f);
    *reinterpret_cast<float2*>(&out[(long)n * HID + lane * 2]) = r;
}

// ---------------- gather layer 2 (aspects only) fused with classifier ----------------
__global__ __launch_bounds__(256) void k_gather2(const int* __restrict__ asp,
                                                 const int* __restrict__ csr,
                                                 const int* __restrict__ offpost,
                                                 const float* __restrict__ dis,
                                                 const float* __restrict__ t2,
                                                 const float* __restrict__ b2,
                                                 const float* __restrict__ Wc,
                                                 const float* __restrict__ bc,
                                                 float* __restrict__ out) {
    int wave = threadIdx.x >> 6;
    int lane = threadIdx.x & 63;
    int a = blockIdx.x * 4 + wave;
    if (a >= NA) return;
    int n = asp[a];
    int start = (n == 0) ? 0 : offpost[n - 1];
    int end = offpost[n];
    float dn = dis[n];
    float2 acc = make_float2(0.f, 0.f);
    for (int i = start; i < end; ++i) {
        int s = csr[i];
        float w = dis[s] * dn;
        float2 v = *reinterpret_cast<const float2*>(&t2[(long)s * HID + lane * 2]);
        acc.x += w * v.x;
        acc.y += w * v.y;
    }
    float d2 = dn * dn;
    float2 hv = *reinterpret_cast<const float2*>(&t2[(long)n * HID + lane * 2]);
    float vx = acc.x + d2 * hv.x + b2[2 * lane];
    float vy = acc.y + d2 * hv.y + b2[2 * lane + 1];
    float l0 = vx * Wc[(2 * lane) * 3 + 0] + vy * Wc[(2 * lane + 1) * 3 + 0];
    float l1 = vx * Wc[(2 * lane) * 3 + 1] + vy * Wc[(2 * lane + 1) * 3 + 1];
    float l2 = vx * Wc[(2 * lane) * 3 + 2] + vy * Wc[(2 * lane + 1) * 3 + 2];
#pragma unroll
    for (int s = 32; s > 0; s >>= 1) {
        l0 += __shfl_xor(l0, s);
        l1 += __shfl_xor(l1, s);
        l2 += __shfl_xor(l2, s);
    }
    if (lane == 0) {
        out[a * 3 + 0] = l0 + bc[0];
        out[a * 3 + 1] = l1 + bc[1];
        out[a * 3 + 2] = l2 + bc[2];
    }
}

extern "C" void kernel_launch(void* const* d_in, const int* in_sizes, int n_in,
                              void* d_out, int out_size, void* d_ws, size_t ws_size,
                              hipStream_t stream) {
    const float* features = (const float*)d_in[0];
    const int* ei = (const int*)d_in[1];
    const int* src = ei;
    const int* dst = ei + NE;
    const int* asp = (const int*)d_in[2];
    const float* W1 = (const float*)d_in[3];
    const float* b1 = (const float*)d_in[4];
    const float* W2 = (const float*)d_in[5];
    const float* b2 = (const float*)d_in[6];
    const float* Wc = (const float*)d_in[7];
    const float* bc = (const float*)d_in[8];
    float* out = (float*)d_out;

    char* ws = (char*)d_ws;
    float* dis   = (float*)(ws + 0);            // 400000 B
    int*   degi  = (int*)  (ws + 400384);       // 400000 B, reused for Bt after scans
    unsigned short* bt1h = (unsigned short*)(ws + 400384);            // 81920 B
    unsigned short* bt1l = (unsigned short*)(ws + 400384 + 81920);    // 81920 B
    unsigned short* bt2h = (unsigned short*)(ws + 400384 + 163840);   // 32768 B
    unsigned short* bt2l = (unsigned short*)(ws + 400384 + 196608);   // 32768 B (ends 629760 < 800768)
    int*   off   = (int*)  (ws + 800768);       // 400000 B
    int*   blksum= (int*)  (ws + 1201152);      // 1024 B
    int*   csr   = (int*)  (ws + 1202176);      // 6400000 B
    float* bufA  = (float*)(ws + 7602432);      // 51200000 B (h1, then t2)
    float* bufB  = (float*)(ws + 58802432);     // 51200000 B (h2in)

    const int NB = (NN + 1023) / 1024;  // 98

    // degree + norm
    hipMemsetAsync(degi, 0, NN * sizeof(int), stream);
    k_deg<<<(NE + 255) / 256, 256, 0, stream>>>(dst, degi);
    k_dis<<<(NN + 255) / 256, 256, 0, stream>>>(degi, dis);

    // CSR build (degi consumed by scan_local; its space then reused for Bt)
    k_scan_local<<<NB, 1024, 0, stream>>>(degi, off, blksum);
    k_scan_blk<<<1, 128, 0, stream>>>(blksum, NB);
    k_scan_add<<<(NN + 255) / 256, 256, 0, stream>>>(off, blksum);
    k_prepB<<<(KP1 * 128 + 255) / 256, 256, 0, stream>>>(W1, bt1h, bt1l, IN_DIM, KP1);
    k_prepB<<<(KP2 * 128 + 255) / 256, 256, 0, stream>>>(W2, bt2h, bt2l, HID, KP2);
    k_fill<<<(NE + 255) / 256, 256, 0, stream>>>(src, dst, off, csr);

    // layer 1: h1 = X@W1 ; h2in = relu(agg(h1) + dis^2*h1 + b1)
    k_gemm_mfma<IN_DIM, KP1><<<(NN + 127) / 128, 256, 0, stream>>>(features, bt1h, bt1l, bufA, NN);
    k_gather1<<<(NN + 3) / 4, 256, 0, stream>>>(csr, off, dis, bufA, b1, bufB);

    // layer 2: t2 = h2in@W2 ; logits per aspect
    k_gemm_mfma<HID, KP2><<<(NN + 127) / 128, 256, 0, stream>>>(bufB, bt2h, bt2l, bufA, NN);
    k_gather2<<<(NA + 3) / 4, 256, 0, stream>>>(asp, csr, off, dis, bufA, b2, Wc, bc, out);
}

// Round 4
// 390.094 us; speedup vs baseline: 8.1830x; 1.3653x over previous
//
#include <hip/hip_runtime.h>

constexpr int NN = 100000;
constexpr int NE = 1600000;
constexpr int IN_DIM = 300;
constexpr int HID = 128;
constexpr int NA = 2048;
constexpr int KP1 = 320;   // padded K for GEMM1 Bt
constexpr int KP2 = 128;
constexpr int NF_CAP = 50000;   // frontier cap (expected ~29K for this input)

using short8 = __attribute__((ext_vector_type(8))) short;
using f32x4  = __attribute__((ext_vector_type(4))) float;

__device__ inline unsigned short f2bf(float x) {
    unsigned u = __float_as_uint(x);
    unsigned r = u + 0x7FFFu + ((u >> 16) & 1u);
    return (unsigned short)(r >> 16);
}
__device__ inline float bf2f(unsigned short h) {
    return __uint_as_float(((unsigned)h) << 16);
}

// ---------------- degree (int) ----------------
__global__ void k_deg(const int* __restrict__ dst, int* __restrict__ degi) {
    int i = blockIdx.x * blockDim.x + threadIdx.x;
    if (i < NE) atomicAdd(&degi[dst[i]], 1);
}

__global__ void k_dis(const int* __restrict__ degi, float* __restrict__ dis) {
    int i = blockIdx.x * blockDim.x + threadIdx.x;
    if (i < NN) dis[i] = rsqrtf((float)degi[i] + 1.0f);   // +1 self loop
}

// ---------------- hierarchical exclusive scan ----------------
__global__ __launch_bounds__(1024) void k_scan_local(const int* __restrict__ in,
                                                     int* __restrict__ out,
                                                     int* __restrict__ blksum) {
    __shared__ int sh[1024];
    int t = threadIdx.x;
    int base = blockIdx.x * 1024;
    int v = (base + t < NN) ? in[base + t] : 0;
    sh[t] = v;
    __syncthreads();
    for (int s = 1; s < 1024; s <<= 1) {
        int a = (t >= s) ? sh[t - s] : 0;
        __syncthreads();
        sh[t] += a;
        __syncthreads();
    }
    if (base + t < NN) out[base + t] = sh[t] - v;   // exclusive
    if (t == 1023) blksum[blockIdx.x] = sh[1023];
}

__global__ __launch_bounds__(128) void k_scan_blk(int* __restrict__ blksum, int nb) {
    __shared__ int sh[128];
    int t = threadIdx.x;
    int v = (t < nb) ? blksum[t] : 0;
    sh[t] = v;
    __syncthreads();
    for (int s = 1; s < 128; s <<= 1) {
        int a = (t >= s) ? sh[t - s] : 0;
        __syncthreads();
        sh[t] += a;
        __syncthreads();
    }
    if (t < nb) blksum[t] = sh[t] - v;   // exclusive
}

__global__ void k_scan_add(int* __restrict__ out, const int* __restrict__ blksum) {
    int i = blockIdx.x * blockDim.x + threadIdx.x;
    if (i < NN) out[i] += blksum[i >> 10];
}

// ---------------- bucket fill ----------------
__global__ void k_fill(const int* __restrict__ src, const int* __restrict__ dst,
                       int* __restrict__ off, int* __restrict__ csr) {
    int e = blockIdx.x * blockDim.x + threadIdx.x;
    if (e < NE) {
        int d = dst[e];
        int pos = atomicAdd(&off[d], 1);
        csr[pos] = src[e];
    }
}

// ---------------- frontier marking ----------------
__global__ void k_flag2(const int* __restrict__ asp, unsigned char* __restrict__ flags2,
                        int* __restrict__ flags1) {
    int i = blockIdx.x * blockDim.x + threadIdx.x;
    if (i < NA) {
        int n = asp[i];
        flags2[n] = 1;
        flags1[n] = 1;
    }
}

__global__ void k_markF1(const int* __restrict__ src, const int* __restrict__ dst,
                         const unsigned char* __restrict__ flags2, int* __restrict__ flags1) {
    int e = blockIdx.x * blockDim.x + threadIdx.x;
    if (e < NE) {
        if (flags2[dst[e]]) flags1[src[e]] = 1;
    }
}

__global__ void k_compact(const int* __restrict__ flags1, const int* __restrict__ off2,
                          int* __restrict__ list, int* __restrict__ remap, int* __restrict__ nf) {
    int i = blockIdx.x * blockDim.x + threadIdx.x;
    if (i < NN && flags1[i]) {
        int p = off2[i];
        if (p < NF_CAP) { list[p] = i; remap[i] = p; }
    }
    if (i == NN - 1) {
        int tot = off2[i] + flags1[i];
        *nf = (tot < NF_CAP) ? tot : NF_CAP;
    }
}

// ---------------- B pre-split: Bt_hi/Bt_lo[col][Kpad] (bf16) ----------------
__global__ void k_prepB(const float* __restrict__ B, unsigned short* __restrict__ bt_hi,
                        unsigned short* __restrict__ bt_lo, int K, int Kpad) {
    int i = blockIdx.x * blockDim.x + threadIdx.x;
    if (i >= Kpad * 128) return;
    int k = i >> 7, c = i & 127;
    float v = (k < K) ? B[k * 128 + c] : 0.f;
    unsigned short hi = f2bf(v);
    unsigned short lo = f2bf(v - bf2f(hi));
    bt_hi[c * Kpad + k] = hi;
    bt_lo[c * Kpad + k] = lo;
}

// ---------------- split-bf16 MFMA GEMM ----------------
template <int K, int KPAD>
__global__ __launch_bounds__(256) void k_gemm_mfma(const float* __restrict__ A,
        const unsigned short* __restrict__ bt_hi, const unsigned short* __restrict__ bt_lo,
        float* __restrict__ C, int M, const int* __restrict__ Mptr) {
    const int Mv = Mptr ? *Mptr : M;
    const int row0 = blockIdx.x * 128;
    if (row0 >= Mv) return;
    __shared__ float As[128 * 36];
    const int t = threadIdx.x;
    const int w = t >> 6;
    const int l = t & 63;
    const int lr = l & 15;
    const int lg = l >> 4;

    f32x4 acc[2][8];
#pragma unroll
    for (int rt = 0; rt < 2; ++rt)
#pragma unroll
        for (int ct = 0; ct < 8; ++ct) acc[rt][ct] = (f32x4){0.f, 0.f, 0.f, 0.f};

    const int NT = (K + 31) / 32;
    for (int kt = 0; kt < NT; ++kt) {
        const int k0 = kt * 32;
#pragma unroll
        for (int i = t; i < 512; i += 256) {
            int r = i >> 2, q = i & 3;
            int gr = row0 + r;
            float* dp = &As[r * 36 + q * 8];
            const float* sp = &A[(long)gr * K + k0 + q * 8];
            if (gr < Mv && (k0 + q * 8 + 8) <= K) {
                float4 v0 = *(const float4*)(sp);
                float4 v1 = *(const float4*)(sp + 4);
                *(float4*)(dp) = v0;
                *(float4*)(dp + 4) = v1;
            } else {
#pragma unroll
                for (int j = 0; j < 8; ++j)
                    dp[j] = (gr < Mv && (k0 + q * 8 + j) < K) ? sp[j] : 0.f;
            }
        }
        __syncthreads();
        short8 ahi[2], alo[2];
#pragma unroll
        for (int rt = 0; rt < 2; ++rt) {
            const float* p = &As[(w * 32 + rt * 16 + lr) * 36 + lg * 8];
            float4 v0 = *(const float4*)(p);
            float4 v1 = *(const float4*)(p + 4);
            float av[8] = {v0.x, v0.y, v0.z, v0.w, v1.x, v1.y, v1.z, v1.w};
#pragma unroll
            for (int j = 0; j < 8; ++j) {
                unsigned short hi = f2bf(av[j]);
                ahi[rt][j] = (short)hi;
                alo[rt][j] = (short)f2bf(av[j] - bf2f(hi));
            }
        }
#pragma unroll
        for (int ct = 0; ct < 8; ++ct) {
            const int c = ct * 16 + lr;
            const long boff = (long)c * KPAD + k0 + lg * 8;
            short8 bhi = *(const short8*)(&bt_hi[boff]);
            short8 blo = *(const short8*)(&bt_lo[boff]);
#pragma unroll
            for (int rt = 0; rt < 2; ++rt) {
                acc[rt][ct] = __builtin_amdgcn_mfma_f32_16x16x32_bf16(ahi[rt], bhi, acc[rt][ct], 0, 0, 0);
                acc[rt][ct] = __builtin_amdgcn_mfma_f32_16x16x32_bf16(alo[rt], bhi, acc[rt][ct], 0, 0, 0);
                acc[rt][ct] = __builtin_amdgcn_mfma_f32_16x16x32_bf16(ahi[rt], blo, acc[rt][ct], 0, 0, 0);
            }
        }
        __syncthreads();
    }
#pragma unroll
    for (int rt = 0; rt < 2; ++rt)
#pragma unroll
        for (int ct = 0; ct < 8; ++ct)
#pragma unroll
            for (int r = 0; r < 4; ++r) {
                int row = row0 + w * 32 + rt * 16 + lg * 4 + r;
                if (row < Mv) C[(long)row * 128 + ct * 16 + lr] = acc[rt][ct][r];
            }
}

// ---------------- gather layer 1 over frontier (fused epilogue), x4 unrolled ----------------
__global__ __launch_bounds__(256) void k_gather1(const int* __restrict__ list,
                                                 const int* __restrict__ nf,
                                                 const int* __restrict__ csr,
                                                 const int* __restrict__ offpost,
                                                 const float* __restrict__ dis,
                                                 const float* __restrict__ h1,
                                                 const float* __restrict__ b1,
                                                 float* __restrict__ out) {
    int wave = threadIdx.x >> 6;
    int lane = threadIdx.x & 63;
    int idx = blockIdx.x * 4 + wave;
    if (idx >= *nf) return;
    int n = list[idx];
    int start = (n == 0) ? 0 : offpost[n - 1];
    int end = offpost[n];
    float dn = dis[n];
    float ax = 0.f, ay = 0.f;
    int i = start;
    for (; i + 4 <= end; i += 4) {
        int s0 = csr[i], s1 = csr[i + 1], s2 = csr[i + 2], s3 = csr[i + 3];
        float w0 = dis[s0], w1 = dis[s1], w2 = dis[s2], w3 = dis[s3];
        float2 v0 = *(const float2*)&h1[(long)s0 * HID + lane * 2];
        float2 v1 = *(const float2*)&h1[(long)s1 * HID + lane * 2];
        float2 v2 = *(const float2*)&h1[(long)s2 * HID + lane * 2];
        float2 v3 = *(const float2*)&h1[(long)s3 * HID + lane * 2];
        ax += w0 * v0.x + w1 * v1.x + w2 * v2.x + w3 * v3.x;
        ay += w0 * v0.y + w1 * v1.y + w2 * v2.y + w3 * v3.y;
    }
    for (; i < end; ++i) {
        int s = csr[i];
        float w = dis[s];
        float2 v = *(const float2*)&h1[(long)s * HID + lane * 2];
        ax += w * v.x;
        ay += w * v.y;
    }
    float d2 = dn;   // self-loop weight = dis[n]*dis[n]; neighbor terms carry *dn below
    float2 hv = *(const float2*)&h1[(long)n * HID + lane * 2];
    float2 bv = *(const float2*)&b1[lane * 2];
    float rx = fmaxf(dn * (ax + d2 * hv.x) + bv.x, 0.f);
    float ry = fmaxf(dn * (ay + d2 * hv.y) + bv.y, 0.f);
    *reinterpret_cast<float2*>(&out[(long)idx * HID + lane * 2]) = make_float2(rx, ry);
}

// ---------------- gather layer 2 (aspects, remapped) + classifier ----------------
__global__ __launch_bounds__(256) void k_gather2(const int* __restrict__ asp,
                                                 const int* __restrict__ remap,
                                                 const int* __restrict__ csr,
                                                 const int* __restrict__ offpost,
                                                 const float* __restrict__ dis,
                                                 const float* __restrict__ t2,
                                                 const float* __restrict__ b2,
                                                 const float* __restrict__ Wc,
                                                 const float* __restrict__ bc,
                                                 float* __restrict__ out) {
    int wave = threadIdx.x >> 6;
    int lane = threadIdx.x & 63;
    int a = blockIdx.x * 4 + wave;
    if (a >= NA) return;
    int n = asp[a];
    int start = (n == 0) ? 0 : offpost[n - 1];
    int end = offpost[n];
    float dn = dis[n];
    float ax = 0.f, ay = 0.f;
    int i = start;
    for (; i + 4 <= end; i += 4) {
        int s0 = csr[i], s1 = csr[i + 1], s2 = csr[i + 2], s3 = csr[i + 3];
        float w0 = dis[s0], w1 = dis[s1], w2 = dis[s2], w3 = dis[s3];
        int r0 = remap[s0], r1 = remap[s1], r2 = remap[s2], r3 = remap[s3];
        float2 v0 = *(const float2*)&t2[(long)r0 * HID + lane * 2];
        float2 v1 = *(const float2*)&t2[(long)r1 * HID + lane * 2];
        float2 v2 = *(const float2*)&t2[(long)r2 * HID + lane * 2];
        float2 v3 = *(const float2*)&t2[(long)r3 * HID + lane * 2];
        ax += w0 * v0.x + w1 * v1.x + w2 * v2.x + w3 * v3.x;
        ay += w0 * v0.y + w1 * v1.y + w2 * v2.y + w3 * v3.y;
    }
    for (; i < end; ++i) {
        int s = csr[i];
        float w = dis[s];
        float2 v = *(const float2*)&t2[(long)remap[s] * HID + lane * 2];
        ax += w * v.x;
        ay += w * v.y;
    }
    float2 hv = *(const float2*)&t2[(long)remap[n] * HID + lane * 2];
    float vx = dn * (ax + dn * hv.x) + b2[2 * lane];
    float vy = dn * (ay + dn * hv.y) + b2[2 * lane + 1];
    float l0 = vx * Wc[(2 * lane) * 3 + 0] + vy * Wc[(2 * lane + 1) * 3 + 0];
    float l1 = vx * Wc[(2 * lane) * 3 + 1] + vy * Wc[(2 * lane + 1) * 3 + 1];
    float l2 = vx * Wc[(2 * lane) * 3 + 2] + vy * Wc[(2 * lane + 1) * 3 + 2];
#pragma unroll
    for (int s = 32; s > 0; s >>= 1) {
        l0 += __shfl_xor(l0, s);
        l1 += __shfl_xor(l1, s);
        l2 += __shfl_xor(l2, s);
    }
    if (lane == 0) {
        out[a * 3 + 0] = l0 + bc[0];
        out[a * 3 + 1] = l1 + bc[1];
        out[a * 3 + 2] = l2 + bc[2];
    }
}

extern "C" void kernel_launch(void* const* d_in, const int* in_sizes, int n_in,
                              void* d_out, int out_size, void* d_ws, size_t ws_size,
                              hipStream_t stream) {
    const float* features = (const float*)d_in[0];
    const int* ei = (const int*)d_in[1];
    const int* src = ei;
    const int* dst = ei + NE;
    const int* asp = (const int*)d_in[2];
    const float* W1 = (const float*)d_in[3];
    const float* b1 = (const float*)d_in[4];
    const float* W2 = (const float*)d_in[5];
    const float* b2 = (const float*)d_in[6];
    const float* Wc = (const float*)d_in[7];
    const float* bc = (const float*)d_in[8];
    float* out = (float*)d_out;

    char* ws = (char*)d_ws;
    float* dis   = (float*)(ws + 0);                        // 400000
    int*   degi  = (int*)  (ws + 400384);                   // 400000 (dead after scan)
    unsigned short* bt1h = (unsigned short*)(ws + 400384);          // 81920 (reuses degi)
    unsigned short* bt1l = (unsigned short*)(ws + 400384 + 81920);  // 81920
    unsigned short* bt2h = (unsigned short*)(ws + 400384 + 163840); // 32768
    unsigned short* bt2l = (unsigned short*)(ws + 400384 + 196608); // 32768 (ends 629760)
    unsigned char* flags2 = (unsigned char*)(ws + 629760);  // 100000 (ends 729760, reuses degi tail)
    int*   off   = (int*)  (ws + 800768);                   // 400000 (CSR offsets -> offpost)
    int*   blksum  = (int*)(ws + 1201152);                  // 1024
    int*   blksum2 = (int*)(ws + 1202176);                  // 1024
    int*   nf    = (int*)  (ws + 1203200);                  // 128
    int*   csr   = (int*)  (ws + 1203328);                  // 6400000 (ends 7603328)
    int*   flags1= (int*)  (ws + 7603328);                  // 400000
    int*   off2  = (int*)  (ws + 8003328);                  // 400000
    int*   list  = (int*)  (ws + 8403328);                  // 400000
    int*   remap = (int*)  (ws + 8803328);                  // 400000 (ends 9203328)
    float* bufA  = (float*)(ws + 9203328);                  // 51200000 (h1, then t2_c)
    float* bufB  = (float*)(ws + 60403328);                 // NF_CAP*128*4 = 25600000 (h2in_c)

    const int NB = (NN + 1023) / 1024;  // 98

    // degree + norm
    hipMemsetAsync(degi, 0, NN * sizeof(int), stream);
    hipMemsetAsync(flags1, 0, NN * sizeof(int), stream);
    k_deg<<<(NE + 255) / 256, 256, 0, stream>>>(dst, degi);
    k_dis<<<(NN + 255) / 256, 256, 0, stream>>>(degi, dis);

    // CSR offsets (consumes degi)
    k_scan_local<<<NB, 1024, 0, stream>>>(degi, off, blksum);
    k_scan_blk<<<1, 128, 0, stream>>>(blksum, NB);
    k_scan_add<<<(NN + 255) / 256, 256, 0, stream>>>(off, blksum);

    // degi space now free: B pre-split + aspect flags
    k_prepB<<<(KP1 * 128 + 255) / 256, 256, 0, stream>>>(W1, bt1h, bt1l, IN_DIM, KP1);
    k_prepB<<<(KP2 * 128 + 255) / 256, 256, 0, stream>>>(W2, bt2h, bt2l, HID, KP2);
    hipMemsetAsync(flags2, 0, NN, stream);
    k_flag2<<<(NA + 255) / 256, 256, 0, stream>>>(asp, flags2, flags1);

    // CSR fill + frontier
    k_fill<<<(NE + 255) / 256, 256, 0, stream>>>(src, dst, off, csr);
    k_markF1<<<(NE + 255) / 256, 256, 0, stream>>>(src, dst, flags2, flags1);
    k_scan_local<<<NB, 1024, 0, stream>>>(flags1, off2, blksum2);
    k_scan_blk<<<1, 128, 0, stream>>>(blksum2, NB);
    k_scan_add<<<(NN + 255) / 256, 256, 0, stream>>>(off2, blksum2);
    k_compact<<<(NN + 255) / 256, 256, 0, stream>>>(flags1, off2, list, remap, nf);

    // layer 1: h1 = X@W1 (all nodes); h2in_c = relu(agg+self+b1) on frontier
    k_gemm_mfma<IN_DIM, KP1><<<(NN + 127) / 128, 256, 0, stream>>>(features, bt1h, bt1l, bufA, NN, nullptr);
    k_gather1<<<(NF_CAP + 3) / 4, 256, 0, stream>>>(list, nf, csr, off, dis, bufA, b1, bufB);

    // layer 2: t2_c = h2in_c@W2 (frontier rows); logits per aspect
    k_gemm_mfma<HID, KP2><<<(NF_CAP + 127) / 128, 256, 0, stream>>>(bufB, bt2h, bt2l, bufA, 0, nf);
    k_gather2<<<(NA + 3) / 4, 256, 0, stream>>>(asp, remap, csr, off, dis, bufA, b2, Wc, bc, out);
}

// Round 5
// 283.889 us; speedup vs baseline: 11.2443x; 1.3741x over previous
//
#include <hip/hip_runtime.h>

constexpr int NN = 100000;
constexpr int NE = 1600000;
constexpr int IN_DIM = 300;
constexpr int HID = 128;
constexpr int NA = 2048;
constexpr int KP1 = 320;   // padded K for GEMM1 Bt
constexpr int KP2 = 128;
constexpr int NF_CAP = 50000;   // frontier cap (expected ~29K for this input)

using short8 = __attribute__((ext_vector_type(8))) short;
using f32x4  = __attribute__((ext_vector_type(4))) float;

__device__ inline unsigned short f2bf(float x) {
    unsigned u = __float_as_uint(x);
    unsigned r = u + 0x7FFFu + ((u >> 16) & 1u);
    return (unsigned short)(r >> 16);
}
__device__ inline float bf2f(unsigned short h) {
    return __uint_as_float(((unsigned)h) << 16);
}

// ---------------- aspect flags ----------------
__global__ void k_flag2(const int* __restrict__ asp, unsigned char* __restrict__ flags2,
                        int* __restrict__ flags1) {
    int i = blockIdx.x * blockDim.x + threadIdx.x;
    if (i < NA) {
        int n = asp[i];
        flags2[n] = 1;
        flags1[n] = 1;
    }
}

// ---------------- fused degree count + frontier mark (one edge pass) ----------------
__global__ void k_deg_mark(const int* __restrict__ src, const int* __restrict__ dst,
                           const unsigned char* __restrict__ flags2,
                           int* __restrict__ degi, int* __restrict__ flags1) {
    int e = blockIdx.x * blockDim.x + threadIdx.x;
    if (e < NE) {
        int d = dst[e];
        atomicAdd(&degi[d], 1);
        if (flags2[d]) flags1[src[e]] = 1;
    }
}

__global__ void k_dis(const int* __restrict__ degi, float* __restrict__ dis) {
    int i = blockIdx.x * blockDim.x + threadIdx.x;
    if (i < NN) dis[i] = rsqrtf((float)degi[i] + 1.0f);   // +1 self loop
}

// ---------------- fused dual hierarchical exclusive scan ----------------
// off  = exclscan(flags1[i] ? degi[i] : 0)   (filtered-CSR offsets)
// off2 = exclscan(flags1[i])                 (frontier compaction)
__global__ __launch_bounds__(1024) void k_scan2_local(const int* __restrict__ degi,
                                                      const int* __restrict__ flags1,
                                                      int* __restrict__ off,
                                                      int* __restrict__ off2,
                                                      int* __restrict__ blksum,
                                                      int* __restrict__ blksum2) {
    __shared__ int sh[1024];
    __shared__ int sh2[1024];
    int t = threadIdx.x;
    int base = blockIdx.x * 1024;
    int ok = (base + t < NN);
    int f = ok ? flags1[base + t] : 0;
    int v = f ? degi[base + t] : 0;
    sh[t] = v;
    sh2[t] = f;
    __syncthreads();
    for (int s = 1; s < 1024; s <<= 1) {
        int a = (t >= s) ? sh[t - s] : 0;
        int a2 = (t >= s) ? sh2[t - s] : 0;
        __syncthreads();
        sh[t] += a;
        sh2[t] += a2;
        __syncthreads();
    }
    if (ok) {
        off[base + t] = sh[t] - v;
        off2[base + t] = sh2[t] - f;
    }
    if (t == 1023) {
        blksum[blockIdx.x] = sh[1023];
        blksum2[blockIdx.x] = sh2[1023];
    }
}

__global__ __launch_bounds__(128) void k_scan2_blk(int* __restrict__ blksum,
                                                   int* __restrict__ blksum2, int nb) {
    __shared__ int sh[128];
    __shared__ int sh2[128];
    int t = threadIdx.x;
    int v = (t < nb) ? blksum[t] : 0;
    int v2 = (t < nb) ? blksum2[t] : 0;
    sh[t] = v;
    sh2[t] = v2;
    __syncthreads();
    for (int s = 1; s < 128; s <<= 1) {
        int a = (t >= s) ? sh[t - s] : 0;
        int a2 = (t >= s) ? sh2[t - s] : 0;
        __syncthreads();
        sh[t] += a;
        sh2[t] += a2;
        __syncthreads();
    }
    if (t < nb) {
        blksum[t] = sh[t] - v;
        blksum2[t] = sh2[t] - v2;
    }
}

__global__ void k_scan2_add(int* __restrict__ off, int* __restrict__ off2,
                            const int* __restrict__ blksum, const int* __restrict__ blksum2) {
    int i = blockIdx.x * blockDim.x + threadIdx.x;
    if (i < NN) {
        off[i] += blksum[i >> 10];
        off2[i] += blksum2[i >> 10];
    }
}

// ---------------- filtered bucket fill (frontier dst only) ----------------
__global__ void k_fill(const int* __restrict__ src, const int* __restrict__ dst,
                       const int* __restrict__ flags1,
                       int* __restrict__ off, int* __restrict__ csr) {
    int e = blockIdx.x * blockDim.x + threadIdx.x;
    if (e < NE) {
        int d = dst[e];
        if (flags1[d]) {
            int pos = atomicAdd(&off[d], 1);
            csr[pos] = src[e];
        }
    }
}

__global__ void k_compact(const int* __restrict__ flags1, const int* __restrict__ off2,
                          int* __restrict__ list, int* __restrict__ remap, int* __restrict__ nf) {
    int i = blockIdx.x * blockDim.x + threadIdx.x;
    if (i < NN && flags1[i]) {
        int p = off2[i];
        if (p < NF_CAP) { list[p] = i; remap[i] = p; }
    }
    if (i == NN - 1) {
        int tot = off2[i] + flags1[i];
        *nf = (tot < NF_CAP) ? tot : NF_CAP;
    }
}

// ---------------- B pre-split: Bt_hi/Bt_lo[col][Kpad] (bf16) ----------------
__global__ void k_prepB(const float* __restrict__ B, unsigned short* __restrict__ bt_hi,
                        unsigned short* __restrict__ bt_lo, int K, int Kpad) {
    int i = blockIdx.x * blockDim.x + threadIdx.x;
    if (i >= Kpad * 128) return;
    int k = i >> 7, c = i & 127;
    float v = (k < K) ? B[k * 128 + c] : 0.f;
    unsigned short hi = f2bf(v);
    unsigned short lo = f2bf(v - bf2f(hi));
    bt_hi[c * Kpad + k] = hi;
    bt_lo[c * Kpad + k] = lo;
}

// ---------------- split-bf16 MFMA GEMM ----------------
template <int K, int KPAD>
__global__ __launch_bounds__(256) void k_gemm_mfma(const float* __restrict__ A,
        const unsigned short* __restrict__ bt_hi, const unsigned short* __restrict__ bt_lo,
        float* __restrict__ C, int M, const int* __restrict__ Mptr) {
    const int Mv = Mptr ? *Mptr : M;
    const int row0 = blockIdx.x * 128;
    if (row0 >= Mv) return;
    __shared__ float As[128 * 36];
    const int t = threadIdx.x;
    const int w = t >> 6;
    const int l = t & 63;
    const int lr = l & 15;
    const int lg = l >> 4;

    f32x4 acc[2][8];
#pragma unroll
    for (int rt = 0; rt < 2; ++rt)
#pragma unroll
        for (int ct = 0; ct < 8; ++ct) acc[rt][ct] = (f32x4){0.f, 0.f, 0.f, 0.f};

    const int NT = (K + 31) / 32;
    for (int kt = 0; kt < NT; ++kt) {
        const int k0 = kt * 32;
#pragma unroll
        for (int i = t; i < 512; i += 256) {
            int r = i >> 2, q = i & 3;
            int gr = row0 + r;
            float* dp = &As[r * 36 + q * 8];
            const float* sp = &A[(long)gr * K + k0 + q * 8];
            if (gr < Mv && (k0 + q * 8 + 8) <= K) {
                float4 v0 = *(const float4*)(sp);
                float4 v1 = *(const float4*)(sp + 4);
                *(float4*)(dp) = v0;
                *(float4*)(dp + 4) = v1;
            } else {
#pragma unroll
                for (int j = 0; j < 8; ++j)
                    dp[j] = (gr < Mv && (k0 + q * 8 + j) < K) ? sp[j] : 0.f;
            }
        }
        __syncthreads();
        short8 ahi[2], alo[2];
#pragma unroll
        for (int rt = 0; rt < 2; ++rt) {
            const float* p = &As[(w * 32 + rt * 16 + lr) * 36 + lg * 8];
            float4 v0 = *(const float4*)(p);
            float4 v1 = *(const float4*)(p + 4);
            float av[8] = {v0.x, v0.y, v0.z, v0.w, v1.x, v1.y, v1.z, v1.w};
#pragma unroll
            for (int j = 0; j < 8; ++j) {
                unsigned short hi = f2bf(av[j]);
                ahi[rt][j] = (short)hi;
                alo[rt][j] = (short)f2bf(av[j] - bf2f(hi));
            }
        }
#pragma unroll
        for (int ct = 0; ct < 8; ++ct) {
            const int c = ct * 16 + lr;
            const long boff = (long)c * KPAD + k0 + lg * 8;
            short8 bhi = *(const short8*)(&bt_hi[boff]);
            short8 blo = *(const short8*)(&bt_lo[boff]);
#pragma unroll
            for (int rt = 0; rt < 2; ++rt) {
                acc[rt][ct] = __builtin_amdgcn_mfma_f32_16x16x32_bf16(ahi[rt], bhi, acc[rt][ct], 0, 0, 0);
                acc[rt][ct] = __builtin_amdgcn_mfma_f32_16x16x32_bf16(alo[rt], bhi, acc[rt][ct], 0, 0, 0);
                acc[rt][ct] = __builtin_amdgcn_mfma_f32_16x16x32_bf16(ahi[rt], blo, acc[rt][ct], 0, 0, 0);
            }
        }
        __syncthreads();
    }
#pragma unroll
    for (int rt = 0; rt < 2; ++rt)
#pragma unroll
        for (int ct = 0; ct < 8; ++ct)
#pragma unroll
            for (int r = 0; r < 4; ++r) {
                int row = row0 + w * 32 + rt * 16 + lg * 4 + r;
                if (row < Mv) C[(long)row * 128 + ct * 16 + lr] = acc[rt][ct][r];
            }
}

// ---------------- gather layer 1 over frontier (fused epilogue), x4 unrolled ----------------
__global__ __launch_bounds__(256) void k_gather1(const int* __restrict__ list,
                                                 const int* __restrict__ nf,
                                                 const int* __restrict__ csr,
                                                 const int* __restrict__ offpost,
                                                 const float* __restrict__ dis,
                                                 const float* __restrict__ h1,
                                                 const float* __restrict__ b1,
                                                 float* __restrict__ out) {
    int wave = threadIdx.x >> 6;
    int lane = threadIdx.x & 63;
    int idx = blockIdx.x * 4 + wave;
    if (idx >= *nf) return;
    int n = list[idx];
    int start = (n == 0) ? 0 : offpost[n - 1];
    int end = offpost[n];
    float dn = dis[n];
    float ax = 0.f, ay = 0.f;
    int i = start;
    for (; i + 4 <= end; i += 4) {
        int s0 = csr[i], s1 = csr[i + 1], s2 = csr[i + 2], s3 = csr[i + 3];
        float w0 = dis[s0], w1 = dis[s1], w2 = dis[s2], w3 = dis[s3];
        float2 v0 = *(const float2*)&h1[(long)s0 * HID + lane * 2];
        float2 v1 = *(const float2*)&h1[(long)s1 * HID + lane * 2];
        float2 v2 = *(const float2*)&h1[(long)s2 * HID + lane * 2];
        float2 v3 = *(const float2*)&h1[(long)s3 * HID + lane * 2];
        ax += w0 * v0.x + w1 * v1.x + w2 * v2.x + w3 * v3.x;
        ay += w0 * v0.y + w1 * v1.y + w2 * v2.y + w3 * v3.y;
    }
    for (; i < end; ++i) {
        int s = csr[i];
        float w = dis[s];
        float2 v = *(const float2*)&h1[(long)s * HID + lane * 2];
        ax += w * v.x;
        ay += w * v.y;
    }
    float2 hv = *(const float2*)&h1[(long)n * HID + lane * 2];
    float2 bv = *(const float2*)&b1[lane * 2];
    float rx = fmaxf(dn * (ax + dn * hv.x) + bv.x, 0.f);
    float ry = fmaxf(dn * (ay + dn * hv.y) + bv.y, 0.f);
    *reinterpret_cast<float2*>(&out[(long)idx * HID + lane * 2]) = make_float2(rx, ry);
}

// ---------------- gather layer 2 (aspects, remapped) + classifier ----------------
__global__ __launch_bounds__(256) void k_gather2(const int* __restrict__ asp,
                                                 const int* __restrict__ remap,
                                                 const int* __restrict__ csr,
                                                 const int* __restrict__ offpost,
                                                 const float* __restrict__ dis,
                                                 const float* __restrict__ t2,
                                                 const float* __restrict__ b2,
                                                 const float* __restrict__ Wc,
                                                 const float* __restrict__ bc,
                                                 float* __restrict__ out) {
    int wave = threadIdx.x >> 6;
    int lane = threadIdx.x & 63;
    int a = blockIdx.x * 4 + wave;
    if (a >= NA) return;
    int n = asp[a];
    int start = (n == 0) ? 0 : offpost[n - 1];
    int end = offpost[n];
    float dn = dis[n];
    float ax = 0.f, ay = 0.f;
    int i = start;
    for (; i + 4 <= end; i += 4) {
        int s0 = csr[i], s1 = csr[i + 1], s2 = csr[i + 2], s3 = csr[i + 3];
        float w0 = dis[s0], w1 = dis[s1], w2 = dis[s2], w3 = dis[s3];
        int r0 = remap[s0], r1 = remap[s1], r2 = remap[s2], r3 = remap[s3];
        float2 v0 = *(const float2*)&t2[(long)r0 * HID + lane * 2];
        float2 v1 = *(const float2*)&t2[(long)r1 * HID + lane * 2];
        float2 v2 = *(const float2*)&t2[(long)r2 * HID + lane * 2];
        float2 v3 = *(const float2*)&t2[(long)r3 * HID + lane * 2];
        ax += w0 * v0.x + w1 * v1.x + w2 * v2.x + w3 * v3.x;
        ay += w0 * v0.y + w1 * v1.y + w2 * v2.y + w3 * v3.y;
    }
    for (; i < end; ++i) {
        int s = csr[i];
        float w = dis[s];
        float2 v = *(const float2*)&t2[(long)remap[s] * HID + lane * 2];
        ax += w * v.x;
        ay += w * v.y;
    }
    float2 hv = *(const float2*)&t2[(long)remap[n] * HID + lane * 2];
    float vx = dn * (ax + dn * hv.x) + b2[2 * lane];
    float vy = dn * (ay + dn * hv.y) + b2[2 * lane + 1];
    float l0 = vx * Wc[(2 * lane) * 3 + 0] + vy * Wc[(2 * lane + 1) * 3 + 0];
    float l1 = vx * Wc[(2 * lane) * 3 + 1] + vy * Wc[(2 * lane + 1) * 3 + 1];
    float l2 = vx * Wc[(2 * lane) * 3 + 2] + vy * Wc[(2 * lane + 1) * 3 + 2];
#pragma unroll
    for (int s = 32; s > 0; s >>= 1) {
        l0 += __shfl_xor(l0, s);
        l1 += __shfl_xor(l1, s);
        l2 += __shfl_xor(l2, s);
    }
    if (lane == 0) {
        out[a * 3 + 0] = l0 + bc[0];
        out[a * 3 + 1] = l1 + bc[1];
        out[a * 3 + 2] = l2 + bc[2];
    }
}

extern "C" void kernel_launch(void* const* d_in, const int* in_sizes, int n_in,
                              void* d_out, int out_size, void* d_ws, size_t ws_size,
                              hipStream_t stream) {
    const float* features = (const float*)d_in[0];
    const int* ei = (const int*)d_in[1];
    const int* src = ei;
    const int* dst = ei + NE;
    const int* asp = (const int*)d_in[2];
    const float* W1 = (const float*)d_in[3];
    const float* b1 = (const float*)d_in[4];
    const float* W2 = (const float*)d_in[5];
    const float* b2 = (const float*)d_in[6];
    const float* Wc = (const float*)d_in[7];
    const float* bc = (const float*)d_in[8];
    float* out = (float*)d_out;

    char* ws = (char*)d_ws;
    float* dis   = (float*)(ws + 0);                        // 400000
    int*   degi  = (int*)  (ws + 400384);                   // 400000 (dead after scan)
    unsigned short* bt1h = (unsigned short*)(ws + 400384);          // 81920 (reuses degi)
    unsigned short* bt1l = (unsigned short*)(ws + 400384 + 81920);  // 81920
    unsigned short* bt2h = (unsigned short*)(ws + 400384 + 163840); // 32768
    unsigned short* bt2l = (unsigned short*)(ws + 400384 + 196608); // 32768 (ends 629760)
    int*   off   = (int*)  (ws + 800768);                   // 400000 (filtered CSR offsets -> offpost)
    int*   blksum  = (int*)(ws + 1201152);                  // 1024
    int*   blksum2 = (int*)(ws + 1202176);                  // 1024
    int*   nf    = (int*)  (ws + 1203200);                  // 128
    int*   csr   = (int*)  (ws + 1203328);                  // 6400000 (ends 7603328)
    int*   flags1= (int*)  (ws + 7603328);                  // 400000
    int*   off2  = (int*)  (ws + 8003328);                  // 400000
    int*   list  = (int*)  (ws + 8403328);                  // 400000
    int*   remap = (int*)  (ws + 8803328);                  // 400000 (ends 9203328)
    float* bufA  = (float*)(ws + 9203328);                  // 51200000 (h1, then t2_c)
    float* bufB  = (float*)(ws + 60403328);                 // NF_CAP*128*4 = 25600000 (h2in_c, ends 86003328)
    unsigned char* flags2 = (unsigned char*)(ws + 86003328);// 100000 (must NOT overlap degi: live before scan)

    const int NB = (NN + 1023) / 1024;  // 98

    // flags + fused degree/mark (one edge pass)
    hipMemsetAsync(degi, 0, NN * sizeof(int), stream);
    hipMemsetAsync(flags1, 0, NN * sizeof(int), stream);
    hipMemsetAsync(flags2, 0, NN, stream);
    k_flag2<<<(NA + 255) / 256, 256, 0, stream>>>(asp, flags2, flags1);
    k_deg_mark<<<(NE + 255) / 256, 256, 0, stream>>>(src, dst, flags2, degi, flags1);
    k_dis<<<(NN + 255) / 256, 256, 0, stream>>>(degi, dis);

    // fused dual scan: filtered-CSR offsets + frontier compaction (consumes degi)
    k_scan2_local<<<NB, 1024, 0, stream>>>(degi, flags1, off, off2, blksum, blksum2);
    k_scan2_blk<<<1, 128, 0, stream>>>(blksum, blksum2, NB);
    k_scan2_add<<<(NN + 255) / 256, 256, 0, stream>>>(off, off2, blksum, blksum2);

    // degi space now free: B pre-split
    k_prepB<<<(KP1 * 128 + 255) / 256, 256, 0, stream>>>(W1, bt1h, bt1l, IN_DIM, KP1);
    k_prepB<<<(KP2 * 128 + 255) / 256, 256, 0, stream>>>(W2, bt2h, bt2l, HID, KP2);

    // frontier compaction + filtered CSR fill
    k_compact<<<(NN + 255) / 256, 256, 0, stream>>>(flags1, off2, list, remap, nf);
    k_fill<<<(NE + 255) / 256, 256, 0, stream>>>(src, dst, flags1, off, csr);

    // layer 1: h1 = X@W1 (all nodes); h2in_c = relu(agg+self+b1) on frontier
    k_gemm_mfma<IN_DIM, KP1><<<(NN + 127) / 128, 256, 0, stream>>>(features, bt1h, bt1l, bufA, NN, nullptr);
    k_gather1<<<(NF_CAP + 3) / 4, 256, 0, stream>>>(list, nf, csr, off, dis, bufA, b1, bufB);

    // layer 2: t2_c = h2in_c@W2 (frontier rows); logits per aspect
    k_gemm_mfma<HID, KP2><<<(NF_CAP + 127) / 128, 256, 0, stream>>>(bufB, bt2h, bt2l, bufA, 0, nf);
    k_gather2<<<(NA + 3) / 4, 256, 0, stream>>>(asp, remap, csr, off, dis, bufA, b2, Wc, bc, out);
}